// Round 11
// baseline (123.472 us; speedup 1.0000x reference)
//
#include <hip/hip_runtime.h>
#include <hip/hip_bf16.h>
#include <hip/hip_cooperative_groups.h>

namespace cg = cooperative_groups;

// Problem constants (match reference)
#define Bb   32
#define Nn   65536
#define Dd   16
#define Hh   64
#define Mm   32
#define OUTn 3

#define TPB    512                  // 8 waves/block
#define CHUNK  256                  // nodes per LDS chunk (16 KiB fp32)
#define NCH    32                   // chunks per block
#define SEGN   (CHUNK * NCH)        // 8192 nodes per block
#define NBLK   ((Bb * Nn) / SEGN)   // 256 blocks  (== #CUs: coop-safe even at
                                    //  1 block/CU under 64KiB-LDS occupancy calc)
#define NWAVES (NBLK * 8)           // 2048 waves
#define WPBATCH (NWAVES / Bb)       // 64 partial-rows per batch
#define NSEG   65                   // 64 knots -> 65 segments

typedef __attribute__((ext_vector_type(8)))  __bf16 bf16x8;
typedef __attribute__((ext_vector_type(4)))  __bf16 bf16x4;
typedef __attribute__((ext_vector_type(16))) float  f32x16;
typedef __attribute__((ext_vector_type(4)))  float  f32x4;

static __device__ inline void split_bf(float w, __bf16& hi, __bf16& lo) {
    hi = (__bf16)w;                 // RNE hardware cvt
    lo = (__bf16)(w - (float)hi);   // residual
}

// async 16B global->LDS (dest = wave-uniform base + lane*16)
typedef const __attribute__((address_space(1))) unsigned int gu32;
typedef __attribute__((address_space(3))) unsigned int lu32;
static __device__ __forceinline__ void gld16(const float* g, float* l) {
    __builtin_amdgcn_global_load_lds((gu32*)g, (lu32*)l, 16, 0, 0);
}

// ---------------------------------------------------------------------------
// Fused cooperative kernel (LDS 48KiB: 2x16KiB staging + 16KiB x_last):
//   Phase A: MFMA message-sum over this block's 8192 nodes; x_last -> LDS.
//   grid.sync
//   Phase B: blocks 0..31 reduce partials + build per-batch PWL tables.
//   grid.sync
//   Phase C: PWL eval (x from LDS), write out.
__global__ __launch_bounds__(TPB) void k_fused(
    const float* __restrict__ in,
    const float* __restrict__ mw1, const float* __restrict__ mb1,
    const float* __restrict__ mw2, const float* __restrict__ mb2,
    const float* __restrict__ iw1, const float* __restrict__ ib1,
    const float* __restrict__ iw2, const float* __restrict__ ib2,
    float* __restrict__ out,
    float* __restrict__ partials, float* __restrict__ knotsG,
    float* __restrict__ segG)
{
    cg::grid_group grid = cg::this_grid();

    __shared__ float  lds[2][CHUNK * Dd];           // 32 KiB staging
    __shared__ __bf16 xs[SEGN];                     // 16 KiB x_last, lives A->C

    const int tid  = threadIdx.x;
    const int lane = tid & 63;
    const int w    = tid >> 6;                      // wave in block (0..7)
    const int l31  = lane & 31;
    const int half = lane >> 5;
    const size_t blk0 = (size_t)blockIdx.x * SEGN;  // first node of this block

    // ---------------- Phase A ----------------
    {
        // B fragments: B[k][col], k = 8*half + e. hi/lo split kills weight bias.
        bf16x8 bhiA, bloA, bhiB, bloB;
#pragma unroll
        for (int e = 0; e < 8; ++e) {
            const int k = 8 * half + e;
            __bf16 h, l;
            split_bf(mw1[k * Hh + l31], h, l);        bhiA[e] = h; bloA[e] = l;
            split_bf(mw1[k * Hh + 32 + l31], h, l);   bhiB[e] = h; bloB[e] = l;
        }
        const float biasA = mb1[l31];
        const float biasB = mb1[32 + l31];

        float hsumA = 0.f, hsumB = 0.f;

        // stage chunk c: 1024 granules (16B), granule g = q*CHUNK + node.
        // thread tid stages g = tid and g = tid + TPB (LDS dest = wave-uniform
        // base + lane*16 for both halves).
        auto stage = [&](int bf, int c) {
            const float* base = in + (blk0 + (size_t)c * CHUNK) * Dd;
#pragma unroll
            for (int gi = 0; gi < 2; ++gi) {
                const int g  = tid + gi * TPB;
                const int q  = g >> 8;
                const int nd = g & 255;
                gld16(base + (size_t)nd * Dd + q * 4, &lds[bf][(size_t)g * 4]);
            }
        };

        int cur = 0;
        stage(0, 0);
        __syncthreads();                            // chunk 0 ready

#pragma unroll 1
        for (int c = 0; c < NCH; ++c) {
            if (c + 1 < NCH) stage(cur ^ 1, c + 1); // prefetch next chunk

            // one 32-node MFMA tile per wave: nodes [w*32, w*32+32)
            const int nb = w * 32 + l31;
            const int q0 = half * 2;
            f32x4 v0 = *(const f32x4*)&lds[cur][(size_t)(q0 * CHUNK + nb) * 4];
            f32x4 v1 = *(const f32x4*)&lds[cur][(size_t)((q0 + 1) * CHUNK + nb) * 4];

            bf16x8 a;
            a[0] = (__bf16)v0[0]; a[1] = (__bf16)v0[1];
            a[2] = (__bf16)v0[2]; a[3] = (__bf16)v0[3];
            a[4] = (__bf16)v1[0]; a[5] = (__bf16)v1[1];
            a[6] = (__bf16)v1[2]; a[7] = (__bf16)v1[3];

            f32x16 z{};
            f32x16 accA = __builtin_amdgcn_mfma_f32_32x32x16_bf16(a, bloA, z, 0, 0, 0);
            accA        = __builtin_amdgcn_mfma_f32_32x32x16_bf16(a, bhiA, accA, 0, 0, 0);
            f32x16 accB = __builtin_amdgcn_mfma_f32_32x32x16_bf16(a, bloB, z, 0, 0, 0);
            accB        = __builtin_amdgcn_mfma_f32_32x32x16_bf16(a, bhiB, accB, 0, 0, 0);

#pragma unroll
            for (int r = 0; r < 16; ++r) {
                accA[r] = fmaxf(accA[r] + biasA, 0.f);
                accB[r] = fmaxf(accB[r] + biasB, 0.f);
            }
#pragma unroll
            for (int st = 8; st >= 1; st >>= 1)
#pragma unroll
                for (int r = 0; r < st; ++r) {
                    accA[r] += accA[r + st];
                    accB[r] += accB[r + st];
                }
            hsumA += accA[0]; hsumB += accB[0];

            // x_last: half=1 lanes hold feat 15 of node nb in v1[3]
            float x15 = __shfl_xor(v1[3], 32, 64);
            if (lane < 32)
                xs[c * CHUNK + w * 32 + lane] = (__bf16)x15;

            __syncthreads();   // drains staged loads; releases cur
            cur ^= 1;
        }

        hsumA += __shfl_xor(hsumA, 32, 64);
        hsumB += __shfl_xor(hsumB, 32, 64);
        const int wid = blockIdx.x * 8 + w;
        partials[(size_t)wid * Hh + lane] = (lane < 32) ? hsumA : hsumB;
    }

    grid.sync();

    // ---------------- Phase B (blocks 0..31) ----------------
    if (blockIdx.x < Bb) {
        float* ov    = &lds[0][0];                  // overlay scratch (4096 floats)
        float* sHs   = ov;                          // 64
        float* sMs   = ov + 64;                     // 32
        float* sBase = ov + 96;                     // 64
        float* sW    = ov + 160;                    // 64
        float* sKn   = ov + 224;                    // 64
        float* sSort = ov + 288;                    // 64
        float* sIw2  = ov + 352;                    // 192
        float (*red)[Hh] = (float (*)[Hh])(ov + 544);  // 8 x 64

        const int b = blockIdx.x;
        const int t = tid;
        const int h = t & 63, slice = t >> 6;       // 8 slices x 8 rows

        float s = 0.f;
        const float* p = partials + ((size_t)b * WPBATCH + slice * 8) * Hh + h;
#pragma unroll
        for (int ww = 0; ww < 8; ++ww) s += p[(size_t)ww * Hh];
        red[slice][h] = s;
        for (int i = t; i < Hh * OUTn; i += TPB) sIw2[i] = iw2[i];
        __syncthreads();

        if (t < Hh) {
            float v = 0.f;
#pragma unroll
            for (int sl = 0; sl < 8; ++sl) v += red[sl][t];
            sHs[t] = v;
        }
        __syncthreads();

        if (t < Mm) {
            float v = (float)Nn * mb2[t];
            for (int hh = 0; hh < Hh; ++hh) v = fmaf(sHs[hh], mw2[hh * Mm + t], v);
            sMs[t] = v;
        }
        __syncthreads();

        if (t < Hh) {
            float bs = ib1[t];
            for (int m = 0; m < Mm; ++m) bs = fmaf(sMs[m], iw1[m * Hh + t], bs);
            float wv = iw1[Mm * Hh + t];
            sBase[t] = bs; sW[t] = wv;
            float k = (wv != 0.f) ? (-bs / wv) : 1e15f;
            if (!(fabsf(k) < 1e15f)) k = 1e15f;     // NaN/inf guard
            sKn[t] = k;
        }
        __syncthreads();

        if (t < Hh) {                               // rank sort (64 values)
            float k = sKn[t];
            int r = 0;
            for (int j = 0; j < Hh; ++j) {
                float kj = sKn[j];
                r += (kj < k || (kj == k && j < t)) ? 1 : 0;
            }
            sSort[r] = k;
        }
        __syncthreads();

        if (t < Hh) knotsG[(size_t)b * Hh + t] = sSort[t];
        if (t < NSEG) {
            float lo = (t == 0)  ? sSort[0] - 1.0f      : sSort[t - 1];
            float hi = (t == Hh) ? sSort[Hh - 1] + 1.0f : sSort[t];
            float m  = 0.5f * lo + 0.5f * hi;
            float A0 = ib2[0], A1 = ib2[1], A2 = ib2[2], B0 = 0.f, B1 = 0.f, B2 = 0.f;
            for (int hh = 0; hh < Hh; ++hh) {
                float bs = sBase[hh], wv = sW[hh];
                if (fmaf(wv, m, bs) > 0.f) {
                    A0 = fmaf(bs, sIw2[hh * 3 + 0], A0);
                    A1 = fmaf(bs, sIw2[hh * 3 + 1], A1);
                    A2 = fmaf(bs, sIw2[hh * 3 + 2], A2);
                    B0 = fmaf(wv, sIw2[hh * 3 + 0], B0);
                    B1 = fmaf(wv, sIw2[hh * 3 + 1], B1);
                    B2 = fmaf(wv, sIw2[hh * 3 + 2], B2);
                }
            }
            float* sg = segG + (size_t)b * 6 * NSEG;   // SoA: [6][NSEG]
            sg[0 * NSEG + t] = A0; sg[1 * NSEG + t] = A1; sg[2 * NSEG + t] = A2;
            sg[3 * NSEG + t] = B0; sg[4 * NSEG + t] = B1; sg[5 * NSEG + t] = B2;
        }
    }

    grid.sync();

    // ---------------- Phase C ----------------
    {
        const int bt = blockIdx.x >> 3;             // batch (8 blocks per batch)
        float* ov = &lds[0][0];
        float* sK = ov;                             // 64 knots
        float* sT = ov + Hh;                        // 6*NSEG = 390 floats

        if (tid < Hh) sK[tid] = knotsG[(size_t)bt * Hh + tid];
        for (int i = tid; i < 6 * NSEG; i += TPB) sT[i] = segG[(size_t)bt * 6 * NSEG + i];
        __syncthreads();

#pragma unroll 1
        for (int k = 0; k < SEGN / (TPB * 4); ++k) {    // 4 iters, 4 nodes/thread
            const int ln4 = (k * TPB + tid) * 4;
            bf16x4 xv = *(const bf16x4*)(xs + ln4);
            float o[12];
#pragma unroll
            for (int i = 0; i < 4; ++i) {
                const float x = (float)xv[i];
                int pos = 0;
#pragma unroll
                for (int st = 32; st >= 1; st >>= 1)
                    pos += (sK[pos + st - 1] < x) ? st : 0;
                pos += (sK[pos] < x) ? 1 : 0;           // pos = #knots < x
                o[3 * i + 0] = fmaf(sT[3 * NSEG + pos], x, sT[0 * NSEG + pos]);
                o[3 * i + 1] = fmaf(sT[4 * NSEG + pos], x, sT[1 * NSEG + pos]);
                o[3 * i + 2] = fmaf(sT[5 * NSEG + pos], x, sT[2 * NSEG + pos]);
            }
            f32x4* po = (f32x4*)(out + (blk0 + (size_t)ln4) * 3);
            po[0] = f32x4{o[0], o[1], o[2],  o[3]};
            po[1] = f32x4{o[4], o[5], o[6],  o[7]};
            po[2] = f32x4{o[8], o[9], o[10], o[11]};
        }
    }
}

// ---------------------------------------------------------------------------
extern "C" void kernel_launch(void* const* d_in, const int* in_sizes, int n_in,
                              void* d_out, int out_size, void* d_ws, size_t ws_size,
                              hipStream_t stream) {
    const float* in  = (const float*)d_in[0];
    const float* mw1 = (const float*)d_in[1];
    const float* mb1 = (const float*)d_in[2];
    const float* mw2 = (const float*)d_in[3];
    const float* mb2 = (const float*)d_in[4];
    const float* iw1 = (const float*)d_in[5];
    const float* ib1 = (const float*)d_in[6];
    const float* iw2 = (const float*)d_in[7];
    const float* ib2 = (const float*)d_in[8];
    float* out = (float*)d_out;

    char* ws = (char*)d_ws;
    const size_t PART_SZ = (size_t)NWAVES * Hh * sizeof(float);  // 512 KiB
    float* partials = (float*)(ws);
    float* knotsG   = (float*)(ws + PART_SZ);                    // 8 KiB
    float* segG     = (float*)(ws + PART_SZ + 8192);             // ~49 KiB

    void* args[] = {
        (void*)&in, (void*)&mw1, (void*)&mb1, (void*)&mw2, (void*)&mb2,
        (void*)&iw1, (void*)&ib1, (void*)&iw2, (void*)&ib2, (void*)&out,
        (void*)&partials, (void*)&knotsG, (void*)&segG
    };
    hipLaunchCooperativeKernel((const void*)k_fused, dim3(NBLK), dim3(TPB),
                               args, 0, stream);
}

// Round 12
// 121.168 us; speedup vs baseline: 1.0190x; 1.0190x over previous
//
#include <hip/hip_runtime.h>
#include <hip/hip_bf16.h>
#include <hip/hip_cooperative_groups.h>

namespace cg = cooperative_groups;

// Problem constants (match reference)
#define Bb   32
#define Nn   65536
#define Dd   16
#define Hh   64
#define Mm   32
#define OUTn 3

#define TPB    512                  // 8 waves/block
#define CHUNK  256                  // nodes per LDS chunk (16 KiB fp32)
#define NCH    32                   // chunks per block
#define SEGN   (CHUNK * NCH)        // 8192 nodes per block
#define NBLK   ((Bb * Nn) / SEGN)   // 256 blocks (1/CU even under 64KiB occupancy calc)
#define NWAVES (NBLK * 8)           // 2048 waves
#define WPBATCH (NWAVES / Bb)       // 64 partial-rows per batch
#define NSEG   65                   // 64 knots -> 65 segments
#define NBUF   3                    // LDS chunk buffers (2 chunks in flight)

typedef __attribute__((ext_vector_type(8)))  __bf16 bf16x8;
typedef __attribute__((ext_vector_type(4)))  __bf16 bf16x4;
typedef __attribute__((ext_vector_type(16))) float  f32x16;
typedef __attribute__((ext_vector_type(4)))  float  f32x4;

static __device__ inline void split_bf(float w, __bf16& hi, __bf16& lo) {
    hi = (__bf16)w;                 // RNE hardware cvt
    lo = (__bf16)(w - (float)hi);   // residual
}

// async 16B global->LDS (dest = wave-uniform base + lane*16)
typedef const __attribute__((address_space(1))) unsigned int gu32;
typedef __attribute__((address_space(3))) unsigned int lu32;
static __device__ __forceinline__ void gld16(const float* g, float* l) {
    __builtin_amdgcn_global_load_lds((gu32*)g, (lu32*)l, 16, 0, 0);
}

// ---------------------------------------------------------------------------
// Fused cooperative kernel. LDS = 3x16KiB staging + 16KiB x_last = 64 KiB.
// Phase A uses the T3/T4 counted-vmcnt pipeline: per chunk
//   s_waitcnt vmcnt(2)      -- oldest chunk's 2 gld16 (this wave) retired
//   s_barrier (raw)          -- all waves done waiting + done reading buf being
//                               overwritten (program order); NO vmcnt(0) drain
//   stage(c+2)               -- keep 2 chunks (32 KiB/CU) always in flight
//   compute(c)
__global__ __launch_bounds__(TPB) void k_fused(
    const float* __restrict__ in,
    const float* __restrict__ mw1, const float* __restrict__ mb1,
    const float* __restrict__ mw2, const float* __restrict__ mb2,
    const float* __restrict__ iw1, const float* __restrict__ ib1,
    const float* __restrict__ iw2, const float* __restrict__ ib2,
    float* __restrict__ out,
    float* __restrict__ partials, float* __restrict__ knotsG,
    float* __restrict__ segG)
{
    cg::grid_group grid = cg::this_grid();

    __shared__ float  lds[NBUF][CHUNK * Dd];        // 48 KiB staging
    __shared__ __bf16 xs[SEGN];                     // 16 KiB x_last, lives A->C

    const int tid  = threadIdx.x;
    const int lane = tid & 63;
    const int w    = tid >> 6;                      // wave in block (0..7)
    const int l31  = lane & 31;
    const int half = lane >> 5;
    const size_t blk0 = (size_t)blockIdx.x * SEGN;  // first node of this block

    // ---------------- Phase A ----------------
    {
        // B fragments: B[k][col], k = 8*half + e. hi/lo split kills weight bias.
        bf16x8 bhiA, bloA, bhiB, bloB;
#pragma unroll
        for (int e = 0; e < 8; ++e) {
            const int k = 8 * half + e;
            __bf16 h, l;
            split_bf(mw1[k * Hh + l31], h, l);        bhiA[e] = h; bloA[e] = l;
            split_bf(mw1[k * Hh + 32 + l31], h, l);   bhiB[e] = h; bloB[e] = l;
        }
        const float biasA = mb1[l31];
        const float biasB = mb1[32 + l31];

        float hsumA = 0.f, hsumB = 0.f;

        // stage chunk c into buffer bf: 1024 granules (16B); granule g = q*CHUNK+nd.
        // thread tid stages g = tid and g = tid+TPB (dest = wave base + lane*16).
        auto stage = [&](int bf, int c) {
            const float* base = in + (blk0 + (size_t)c * CHUNK) * Dd;
#pragma unroll
            for (int gi = 0; gi < 2; ++gi) {
                const int g  = tid + gi * TPB;
                const int q  = g >> 8;
                const int nd = g & 255;
                gld16(base + (size_t)nd * Dd + q * 4, &lds[bf][(size_t)g * 4]);
            }
        };

        // one 32-node MFMA tile per wave: nodes [w*32, w*32+32) of chunk c
        auto compute = [&](int bf, int c) {
            const int nb = w * 32 + l31;
            const int q0 = half * 2;
            f32x4 v0 = *(const f32x4*)&lds[bf][(size_t)(q0 * CHUNK + nb) * 4];
            f32x4 v1 = *(const f32x4*)&lds[bf][(size_t)((q0 + 1) * CHUNK + nb) * 4];

            bf16x8 a;
            a[0] = (__bf16)v0[0]; a[1] = (__bf16)v0[1];
            a[2] = (__bf16)v0[2]; a[3] = (__bf16)v0[3];
            a[4] = (__bf16)v1[0]; a[5] = (__bf16)v1[1];
            a[6] = (__bf16)v1[2]; a[7] = (__bf16)v1[3];

            f32x16 z{};
            f32x16 accA = __builtin_amdgcn_mfma_f32_32x32x16_bf16(a, bloA, z, 0, 0, 0);
            accA        = __builtin_amdgcn_mfma_f32_32x32x16_bf16(a, bhiA, accA, 0, 0, 0);
            f32x16 accB = __builtin_amdgcn_mfma_f32_32x32x16_bf16(a, bloB, z, 0, 0, 0);
            accB        = __builtin_amdgcn_mfma_f32_32x32x16_bf16(a, bhiB, accB, 0, 0, 0);

#pragma unroll
            for (int r = 0; r < 16; ++r) {
                accA[r] = fmaxf(accA[r] + biasA, 0.f);
                accB[r] = fmaxf(accB[r] + biasB, 0.f);
            }
#pragma unroll
            for (int st = 8; st >= 1; st >>= 1)
#pragma unroll
                for (int r = 0; r < st; ++r) {
                    accA[r] += accA[r + st];
                    accB[r] += accB[r + st];
                }
            hsumA += accA[0]; hsumB += accB[0];

            // x_last: half=1 lanes hold feat 15 of node nb in v1[3]
            float x15 = __shfl_xor(v1[3], 32, 64);
            if (lane < 32)
                xs[c * CHUNK + w * 32 + lane] = (__bf16)x15;
        };

        stage(0, 0);
        stage(1, 1);

#pragma unroll 1
        for (int c = 0; c < NCH - 1; ++c) {
            asm volatile("s_waitcnt vmcnt(2)" ::: "memory");  // chunk c landed (this wave)
            __builtin_amdgcn_s_barrier();                     // all waves: landed + prev reads done
            __builtin_amdgcn_sched_barrier(0);
            if (c + 2 < NCH) stage((c + 2) % NBUF, c + 2);    // overwrites buf (c-1)%NBUF
            compute(c % NBUF, c);
        }
        asm volatile("s_waitcnt vmcnt(0)" ::: "memory");      // last chunk: full drain
        __builtin_amdgcn_s_barrier();
        __builtin_amdgcn_sched_barrier(0);
        compute((NCH - 1) % NBUF, NCH - 1);

        hsumA += __shfl_xor(hsumA, 32, 64);
        hsumB += __shfl_xor(hsumB, 32, 64);
        const int wid = blockIdx.x * 8 + w;
        partials[(size_t)wid * Hh + lane] = (lane < 32) ? hsumA : hsumB;
    }

    grid.sync();

    // ---------------- Phase B (blocks 0..31) ----------------
    if (blockIdx.x < Bb) {
        float* ov    = &lds[0][0];                  // overlay scratch (4096 floats)
        float* sHs   = ov;                          // 64
        float* sMs   = ov + 64;                     // 32
        float* sBase = ov + 96;                     // 64
        float* sW    = ov + 160;                    // 64
        float* sKn   = ov + 224;                    // 64
        float* sSort = ov + 288;                    // 64
        float* sIw2  = ov + 352;                    // 192
        float (*red)[Hh] = (float (*)[Hh])(ov + 544);  // 8 x 64

        const int b = blockIdx.x;
        const int t = tid;
        const int h = t & 63, slice = t >> 6;       // 8 slices x 8 rows

        float s = 0.f;
        const float* p = partials + ((size_t)b * WPBATCH + slice * 8) * Hh + h;
#pragma unroll
        for (int ww = 0; ww < 8; ++ww) s += p[(size_t)ww * Hh];
        red[slice][h] = s;
        for (int i = t; i < Hh * OUTn; i += TPB) sIw2[i] = iw2[i];
        __syncthreads();

        if (t < Hh) {
            float v = 0.f;
#pragma unroll
            for (int sl = 0; sl < 8; ++sl) v += red[sl][t];
            sHs[t] = v;
        }
        __syncthreads();

        if (t < Mm) {
            float v = (float)Nn * mb2[t];
            for (int hh = 0; hh < Hh; ++hh) v = fmaf(sHs[hh], mw2[hh * Mm + t], v);
            sMs[t] = v;
        }
        __syncthreads();

        if (t < Hh) {
            float bs = ib1[t];
            for (int m = 0; m < Mm; ++m) bs = fmaf(sMs[m], iw1[m * Hh + t], bs);
            float wv = iw1[Mm * Hh + t];
            sBase[t] = bs; sW[t] = wv;
            float k = (wv != 0.f) ? (-bs / wv) : 1e15f;
            if (!(fabsf(k) < 1e15f)) k = 1e15f;     // NaN/inf guard
            sKn[t] = k;
        }
        __syncthreads();

        if (t < Hh) {                               // rank sort (64 values)
            float k = sKn[t];
            int r = 0;
            for (int j = 0; j < Hh; ++j) {
                float kj = sKn[j];
                r += (kj < k || (kj == k && j < t)) ? 1 : 0;
            }
            sSort[r] = k;
        }
        __syncthreads();

        if (t < Hh) knotsG[(size_t)b * Hh + t] = sSort[t];
        if (t < NSEG) {
            float lo = (t == 0)  ? sSort[0] - 1.0f      : sSort[t - 1];
            float hi = (t == Hh) ? sSort[Hh - 1] + 1.0f : sSort[t];
            float m  = 0.5f * lo + 0.5f * hi;
            float A0 = ib2[0], A1 = ib2[1], A2 = ib2[2], B0 = 0.f, B1 = 0.f, B2 = 0.f;
            for (int hh = 0; hh < Hh; ++hh) {
                float bs = sBase[hh], wv = sW[hh];
                if (fmaf(wv, m, bs) > 0.f) {
                    A0 = fmaf(bs, sIw2[hh * 3 + 0], A0);
                    A1 = fmaf(bs, sIw2[hh * 3 + 1], A1);
                    A2 = fmaf(bs, sIw2[hh * 3 + 2], A2);
                    B0 = fmaf(wv, sIw2[hh * 3 + 0], B0);
                    B1 = fmaf(wv, sIw2[hh * 3 + 1], B1);
                    B2 = fmaf(wv, sIw2[hh * 3 + 2], B2);
                }
            }
            float* sg = segG + (size_t)b * 6 * NSEG;   // SoA: [6][NSEG]
            sg[0 * NSEG + t] = A0; sg[1 * NSEG + t] = A1; sg[2 * NSEG + t] = A2;
            sg[3 * NSEG + t] = B0; sg[4 * NSEG + t] = B1; sg[5 * NSEG + t] = B2;
        }
    }

    grid.sync();

    // ---------------- Phase C ----------------
    {
        const int bt = blockIdx.x >> 3;             // batch (8 blocks per batch)
        float* ov = &lds[0][0];
        float* sK = ov;                             // 64 knots
        float* sT = ov + Hh;                        // 6*NSEG = 390 floats

        if (tid < Hh) sK[tid] = knotsG[(size_t)bt * Hh + tid];
        for (int i = tid; i < 6 * NSEG; i += TPB) sT[i] = segG[(size_t)bt * 6 * NSEG + i];
        __syncthreads();

#pragma unroll 1
        for (int k = 0; k < SEGN / (TPB * 4); ++k) {    // 4 iters, 4 nodes/thread
            const int ln4 = (k * TPB + tid) * 4;
            bf16x4 xv = *(const bf16x4*)(xs + ln4);
            float o[12];
#pragma unroll
            for (int i = 0; i < 4; ++i) {
                const float x = (float)xv[i];
                int pos = 0;
#pragma unroll
                for (int st = 32; st >= 1; st >>= 1)
                    pos += (sK[pos + st - 1] < x) ? st : 0;
                pos += (sK[pos] < x) ? 1 : 0;           // pos = #knots < x
                o[3 * i + 0] = fmaf(sT[3 * NSEG + pos], x, sT[0 * NSEG + pos]);
                o[3 * i + 1] = fmaf(sT[4 * NSEG + pos], x, sT[1 * NSEG + pos]);
                o[3 * i + 2] = fmaf(sT[5 * NSEG + pos], x, sT[2 * NSEG + pos]);
            }
            f32x4* po = (f32x4*)(out + (blk0 + (size_t)ln4) * 3);
            po[0] = f32x4{o[0], o[1], o[2],  o[3]};
            po[1] = f32x4{o[4], o[5], o[6],  o[7]};
            po[2] = f32x4{o[8], o[9], o[10], o[11]};
        }
    }
}

// ---------------------------------------------------------------------------
extern "C" void kernel_launch(void* const* d_in, const int* in_sizes, int n_in,
                              void* d_out, int out_size, void* d_ws, size_t ws_size,
                              hipStream_t stream) {
    const float* in  = (const float*)d_in[0];
    const float* mw1 = (const float*)d_in[1];
    const float* mb1 = (const float*)d_in[2];
    const float* mw2 = (const float*)d_in[3];
    const float* mb2 = (const float*)d_in[4];
    const float* iw1 = (const float*)d_in[5];
    const float* ib1 = (const float*)d_in[6];
    const float* iw2 = (const float*)d_in[7];
    const float* ib2 = (const float*)d_in[8];
    float* out = (float*)d_out;

    char* ws = (char*)d_ws;
    const size_t PART_SZ = (size_t)NWAVES * Hh * sizeof(float);  // 512 KiB
    float* partials = (float*)(ws);
    float* knotsG   = (float*)(ws + PART_SZ);                    // 8 KiB
    float* segG     = (float*)(ws + PART_SZ + 8192);             // ~49 KiB

    void* args[] = {
        (void*)&in, (void*)&mw1, (void*)&mb1, (void*)&mw2, (void*)&mb2,
        (void*)&iw1, (void*)&ib1, (void*)&iw2, (void*)&ib2, (void*)&out,
        (void*)&partials, (void*)&knotsG, (void*)&segG
    };
    hipLaunchCooperativeKernel((const void*)k_fused, dim3(NBLK), dim3(TPB),
                               args, 0, stream);
}

// Round 13
// 61.039 us; speedup vs baseline: 2.0229x; 1.9851x over previous
//
#include <hip/hip_runtime.h>
#include <hip/hip_bf16.h>

// Problem constants (match reference)
#define Bb   32
#define Nn   65536
#define Dd   16
#define Hh   64
#define Mm   32
#define OUTn 3

#define NPW   512              // nodes per wave in mphase (16 tiles of 32)
#define NT    (NPW / 32)       // 16 tiles per wave
#define WPB_N (Nn / NPW)       // partial rows per batch = 128
#define TPB   256
#define NSEG  65               // 64 knots -> 65 segments

typedef __attribute__((ext_vector_type(8)))  __bf16 bf16x8;
typedef __attribute__((ext_vector_type(4)))  __bf16 bf16x4;
typedef __attribute__((ext_vector_type(16))) float  f32x16;
typedef __attribute__((ext_vector_type(4)))  float  f32x4;

static __device__ inline void split_bf(float w, __bf16& hi, __bf16& lo) {
    hi = (__bf16)w;                 // RNE hardware cvt
    lo = (__bf16)(w - (float)hi);   // residual
}

// ---------------------------------------------------------------------------
// Phase 1 via MFMA, 4-deep register-ring streaming (no LDS, no barriers):
// consume slot s -> immediately issue tile t+4 into slot s. Consumption in
// issue order => compiler emits counted vmcnt waits; in-flight stays ~flat
// (4 x 2KiB per wave) instead of the barrier-drain sawtooth of R9/R11/R12.
__global__ __launch_bounds__(TPB) void k_mphase(
    const float* __restrict__ in, const float* __restrict__ mw1,
    const float* __restrict__ mb1, float* __restrict__ partials,
    __bf16* __restrict__ xlast)
{
    const int lane = threadIdx.x & 63;
    const int l31  = lane & 31;
    const int half = lane >> 5;                        // k-part: feats 8*half..
    const int wid  = blockIdx.x * (TPB / 64) + (threadIdx.x >> 6);
    const size_t node0 = (size_t)wid * NPW;

    // B fragments: B[k][col], k = 8*half + e. hi/lo split kills weight bias.
    bf16x8 bhiA, bloA, bhiB, bloB;
#pragma unroll
    for (int e = 0; e < 8; ++e) {
        const int k = 8 * half + e;
        __bf16 h, l;
        split_bf(mw1[k * Hh + l31], h, l);        bhiA[e] = h; bloA[e] = l;
        split_bf(mw1[k * Hh + 32 + l31], h, l);   bhiB[e] = h; bloB[e] = l;
    }
    const float biasA = mb1[l31];
    const float biasB = mb1[32 + l31];

    float hsumA = 0.f, hsumB = 0.f;
    // per-lane stream base: lane covers node (tile*32 + l31), feats 8*half..8*half+7
    const float* __restrict__ inw = in + node0 * Dd + (size_t)l31 * Dd + 8 * half;

    // 4-deep ring in named registers (static indexing only -- rule #20)
    f32x4 r0a, r0b, r1a, r1b, r2a, r2b, r3a, r3b;
#define ISSUE(s, t)                                                  \
    r##s##a = *(const f32x4*)(inw + (size_t)(t) * 512);              \
    r##s##b = *(const f32x4*)(inw + (size_t)(t) * 512 + 4)

    // consume one tile: va/vb = 8 feats of node (tile*32+l31), k-half 'half'
    auto consume = [&](f32x4 va, f32x4 vb, int tile) {
        bf16x8 a;
        a[0] = (__bf16)va[0]; a[1] = (__bf16)va[1];
        a[2] = (__bf16)va[2]; a[3] = (__bf16)va[3];
        a[4] = (__bf16)vb[0]; a[5] = (__bf16)vb[1];
        a[6] = (__bf16)vb[2]; a[7] = (__bf16)vb[3];

        f32x16 z{};
        f32x16 accA = __builtin_amdgcn_mfma_f32_32x32x16_bf16(a, bloA, z, 0, 0, 0);
        accA        = __builtin_amdgcn_mfma_f32_32x32x16_bf16(a, bhiA, accA, 0, 0, 0);
        f32x16 accB = __builtin_amdgcn_mfma_f32_32x32x16_bf16(a, bloB, z, 0, 0, 0);
        accB        = __builtin_amdgcn_mfma_f32_32x32x16_bf16(a, bhiB, accB, 0, 0, 0);

#pragma unroll
        for (int r = 0; r < 16; ++r) {
            accA[r] = fmaxf(accA[r] + biasA, 0.f);
            accB[r] = fmaxf(accB[r] + biasB, 0.f);
        }
#pragma unroll
        for (int st = 8; st >= 1; st >>= 1)
#pragma unroll
            for (int r = 0; r < st; ++r) {
                accA[r] += accA[r + st];
                accB[r] += accB[r + st];
            }
        hsumA += accA[0]; hsumB += accB[0];

        // x_last: half=1 lanes hold feat 15 of node (tile*32+l31) in vb[3]
        float x15 = __shfl_xor(vb[3], 32, 64);
        if (lane < 32)
            xlast[node0 + (size_t)tile * 32 + lane] = (__bf16)x15;
    };

    ISSUE(0, 0); ISSUE(1, 1); ISSUE(2, 2); ISSUE(3, 3);

#pragma unroll 1
    for (int g = 0; g < NT / 4; ++g) {               // 4 groups of 4 tiles
        const int t0 = g * 4;
        consume(r0a, r0b, t0 + 0); if (g < NT / 4 - 1) { ISSUE(0, t0 + 4); }
        consume(r1a, r1b, t0 + 1); if (g < NT / 4 - 1) { ISSUE(1, t0 + 5); }
        consume(r2a, r2b, t0 + 2); if (g < NT / 4 - 1) { ISSUE(2, t0 + 6); }
        consume(r3a, r3b, t0 + 3); if (g < NT / 4 - 1) { ISSUE(3, t0 + 7); }
    }
#undef ISSUE

    hsumA += __shfl_xor(hsumA, 32, 64);
    hsumB += __shfl_xor(hsumB, 32, 64);
    partials[(size_t)wid * Hh + lane] = (lane < 32) ? hsumA : hsumB;
}

// ---------------------------------------------------------------------------
// Reduce partials (parallel, coalesced) + build PWL tables.
// One block (256 thr) per batch. out_j(x) = A_j[seg] + B_j[seg]*x.
__global__ __launch_bounds__(256) void k_combine(
    const float* __restrict__ partials,
    const float* __restrict__ mw2, const float* __restrict__ mb2,
    const float* __restrict__ iw1, const float* __restrict__ ib1,
    const float* __restrict__ iw2, const float* __restrict__ ib2,
    float* __restrict__ knotsG, float* __restrict__ segG)
{
    __shared__ float red[4][Hh];
    __shared__ float sHs[Hh], sMs[Mm], sBase[Hh], sW[Hh], sKn[Hh], sSort[Hh];
    __shared__ float sIw2[Hh * OUTn];
    const int b = blockIdx.x;
    const int t = threadIdx.x;              // 0..255
    const int h = t & 63, slice = t >> 6;   // 4 slices x 32 rows

    float s = 0.f;
    const float* p = partials + ((size_t)b * WPB_N + slice * 32) * Hh + h;
#pragma unroll 8
    for (int ww = 0; ww < 32; ++ww) s += p[(size_t)ww * Hh];
    red[slice][h] = s;
    for (int i = t; i < Hh * OUTn; i += 256) sIw2[i] = iw2[i];
    __syncthreads();

    if (t < Hh) sHs[t] = red[0][t] + red[1][t] + red[2][t] + red[3][t];
    __syncthreads();

    if (t < Mm) {
        float v = (float)Nn * mb2[t];
        for (int hh = 0; hh < Hh; ++hh) v = fmaf(sHs[hh], mw2[hh * Mm + t], v);
        sMs[t] = v;
    }
    __syncthreads();

    if (t < Hh) {
        float bs = ib1[t];
        for (int m = 0; m < Mm; ++m) bs = fmaf(sMs[m], iw1[m * Hh + t], bs);
        float w = iw1[Mm * Hh + t];
        sBase[t] = bs; sW[t] = w;
        float k = (w != 0.f) ? (-bs / w) : 1e15f;
        if (!(fabsf(k) < 1e15f)) k = 1e15f;   // NaN/inf guard
        sKn[t] = k;
    }
    __syncthreads();

    if (t < Hh) {                            // rank sort (64 values)
        float k = sKn[t];
        int r = 0;
        for (int j = 0; j < Hh; ++j) {
            float kj = sKn[j];
            r += (kj < k || (kj == k && j < t)) ? 1 : 0;
        }
        sSort[r] = k;
    }
    __syncthreads();

    if (t < Hh) knotsG[(size_t)b * Hh + t] = sSort[t];
    if (t < NSEG) {
        float lo = (t == 0)  ? sSort[0] - 1.0f      : sSort[t - 1];
        float hi = (t == Hh) ? sSort[Hh - 1] + 1.0f : sSort[t];
        float m  = 0.5f * lo + 0.5f * hi;
        float A0 = ib2[0], A1 = ib2[1], A2 = ib2[2], B0 = 0.f, B1 = 0.f, B2 = 0.f;
        for (int hh = 0; hh < Hh; ++hh) {
            float bs = sBase[hh], w = sW[hh];
            if (fmaf(w, m, bs) > 0.f) {
                A0 = fmaf(bs, sIw2[hh * 3 + 0], A0);
                A1 = fmaf(bs, sIw2[hh * 3 + 1], A1);
                A2 = fmaf(bs, sIw2[hh * 3 + 2], A2);
                B0 = fmaf(w,  sIw2[hh * 3 + 0], B0);
                B1 = fmaf(w,  sIw2[hh * 3 + 1], B1);
                B2 = fmaf(w,  sIw2[hh * 3 + 2], B2);
            }
        }
        float* sg = segG + (size_t)b * 6 * NSEG;   // SoA: [6][NSEG]
        sg[0 * NSEG + t] = A0; sg[1 * NSEG + t] = A1; sg[2 * NSEG + t] = A2;
        sg[3 * NSEG + t] = B0; sg[4 * NSEG + t] = B1; sg[5 * NSEG + t] = B2;
    }
}

// ---------------------------------------------------------------------------
// Phase 2: PWL eval. 4 nodes/thread; branchless binary search over 64 knots.
__global__ __launch_bounds__(TPB) void k_iphase(
    const __bf16* __restrict__ xl, const float* __restrict__ knotsG,
    const float* __restrict__ segG, float* __restrict__ out)
{
    __shared__ __align__(16) float sK[Hh];
    __shared__ float sT[6 * NSEG];
    const int t = threadIdx.x;
    const int b = blockIdx.x >> 6;          // 64 blocks per batch (1024 nodes/blk)

    if (t < Hh) sK[t] = knotsG[(size_t)b * Hh + t];
    for (int i = t; i < 6 * NSEG; i += TPB) sT[i] = segG[(size_t)b * 6 * NSEG + i];
    __syncthreads();

    const size_t n0 = ((size_t)blockIdx.x * TPB + t) * 4;
    bf16x4 xv = *(const bf16x4*)(xl + n0);
    float o[12];
#pragma unroll
    for (int i = 0; i < 4; ++i) {
        const float x = (float)xv[i];
        int pos = 0;
#pragma unroll
        for (int st = 32; st >= 1; st >>= 1)
            pos += (sK[pos + st - 1] < x) ? st : 0;
        pos += (sK[pos] < x) ? 1 : 0;       // pos = #knots < x, in [0,64]
        o[3 * i + 0] = fmaf(sT[3 * NSEG + pos], x, sT[0 * NSEG + pos]);
        o[3 * i + 1] = fmaf(sT[4 * NSEG + pos], x, sT[1 * NSEG + pos]);
        o[3 * i + 2] = fmaf(sT[5 * NSEG + pos], x, sT[2 * NSEG + pos]);
    }
    f32x4* po = (f32x4*)(out + n0 * 3);
    po[0] = f32x4{o[0], o[1], o[2],  o[3]};
    po[1] = f32x4{o[4], o[5], o[6],  o[7]};
    po[2] = f32x4{o[8], o[9], o[10], o[11]};
}

// ---------------------------------------------------------------------------
extern "C" void kernel_launch(void* const* d_in, const int* in_sizes, int n_in,
                              void* d_out, int out_size, void* d_ws, size_t ws_size,
                              hipStream_t stream) {
    const float* in  = (const float*)d_in[0];
    const float* mw1 = (const float*)d_in[1];
    const float* mb1 = (const float*)d_in[2];
    const float* mw2 = (const float*)d_in[3];
    const float* mb2 = (const float*)d_in[4];
    const float* iw1 = (const float*)d_in[5];
    const float* ib1 = (const float*)d_in[6];
    const float* iw2 = (const float*)d_in[7];
    const float* ib2 = (const float*)d_in[8];
    float* out = (float*)d_out;

    char* ws = (char*)d_ws;
    const size_t PART_SZ = (size_t)Bb * WPB_N * Hh * sizeof(float);  // 1 MiB
    float*  partials = (float*)(ws);
    float*  knotsG   = (float*)(ws + PART_SZ);             // 8 KiB
    float*  segG     = (float*)(ws + PART_SZ + 8192);      // ~49 KiB
    __bf16* xl       = (__bf16*)(ws + PART_SZ + 131072);   // 4 MiB

    const int nwaves  = (Bb * Nn) / NPW;          // 4096
    const int nblocks = nwaves / (TPB / 64);      // 1024

    hipLaunchKernelGGL(k_mphase, dim3(nblocks), dim3(TPB), 0, stream,
                       in, mw1, mb1, partials, xl);
    hipLaunchKernelGGL(k_combine, dim3(Bb), dim3(256), 0, stream,
                       partials, mw2, mb2, iw1, ib1, iw2, ib2, knotsG, segG);
    hipLaunchKernelGGL(k_iphase, dim3((Bb * Nn) / (TPB * 4)), dim3(TPB), 0, stream,
                       xl, knotsG, segG, out);
}